// Round 10
// baseline (300.477 us; speedup 1.0000x reference)
//
#include <hip/hip_runtime.h>
#include <hip/hip_bf16.h>

#define N_FEATS_IN 128
#define BK_BITS 8
#define BK_SIZE 256      // nodes per bucket
#define EPB 4096         // edges per histogram/scatter block
#define MAXNB 512        // max buckets (N <= 131072)

typedef _Float16 h8 __attribute__((ext_vector_type(8)));
typedef float    f4v __attribute__((ext_vector_type(4)));
typedef float    f8v __attribute__((ext_vector_type(8)));

// ---------------------------------------------------------------------------
// scan / reduce helpers
// ---------------------------------------------------------------------------
__device__ inline int wave_incl_scan(int v) {
    const int lane = threadIdx.x & 63;
    for (int off = 1; off < 64; off <<= 1) {
        int u = __shfl_up(v, off, 64);
        if (lane >= off) v += u;
    }
    return v;
}

// NW-wave (NW*64-thread) block exclusive scan; ws = LDS int[NW]; syncs
// internally after the ws write. Caller must __syncthreads() before reuse.
template <int NW>
__device__ inline int block_excl_scan(int s, int* ws, int* total) {
    const int lane = threadIdx.x & 63, wid = threadIdx.x >> 6;
    int inc = wave_incl_scan(s);
    if (lane == 63) ws[wid] = inc;
    __syncthreads();
    int woff = 0;
#pragma unroll
    for (int w = 0; w < NW; ++w) woff += (w < wid) ? ws[w] : 0;
    if (total) {
        int tt = 0;
#pragma unroll
        for (int w = 0; w < NW; ++w) tt += ws[w];
        *total = tt;
    }
    return woff + inc - s;
}

// ---------------------------------------------------------------------------
// K1: per-block LDS bucket histograms of dst>>8 AND src>>8 (no global
//     atomics). 512 threads. + fused one-shot W1/W2 pre-swizzle.
// ---------------------------------------------------------------------------
__global__ __launch_bounds__(512) void hist_kernel(
    const int* __restrict__ src, const int* __restrict__ dst,
    int* __restrict__ bh_d, int* __restrict__ bh_s,
    const float* __restrict__ W1, const float* __restrict__ W2,
    _Float16* __restrict__ wf1g, _Float16* __restrict__ wf2g,
    int E, int NB) {
    __shared__ int hd[MAXNB];
    __shared__ int hs[MAXNB];
    const int t = threadIdx.x;

    // ---- W pre-swizzle: B-fragment layout of mfma_f32_16x16x32_f16 ----
    const int widx = blockIdx.x * 512 + t;
    if (widx < 128 * 128) {                       // W1: K=128, OC=128
        const int i = widx;
        const int k = i >> 7, c = i & 127;
        const int tt = c >> 4, s = k >> 5, q = (k >> 3) & 3, j = k & 7;
        wf1g[(((tt * 4 + s) * 4 + q) * 16 + (c & 15)) * 8 + j] =
            (_Float16)W1[i];
    } else if (widx < 128 * 128 + 128 * 64) {     // W2: K=128, OC=64
        const int i = widx - 128 * 128;
        const int k = i >> 6, c = i & 63;
        const int tt = c >> 4, s = k >> 5, q = (k >> 3) & 3, j = k & 7;
        wf2g[(((tt * 4 + s) * 4 + q) * 16 + (c & 15)) * 8 + j] =
            (_Float16)W2[i];
    }

    for (int i = t; i < NB; i += 512) { hd[i] = 0; hs[i] = 0; }
    __syncthreads();
    const int base = blockIdx.x * EPB;
    const int end = min(base + EPB, E);
    for (int e = base + t; e < end; e += 512) {
        atomicAdd(&hd[dst[e] >> BK_BITS], 1);
        atomicAdd(&hs[src[e] >> BK_BITS], 1);
    }
    __syncthreads();
    for (int i = t; i < NB; i += 512) {
        bh_d[(size_t)blockIdx.x * NB + i] = hd[i];
        bh_s[(size_t)blockIdx.x * NB + i] = hs[i];
    }
}

// K2a: 4 columns per block (adjacent cols share 64B lines): in-place local
//      exclusive prefix over blk of bh[blk][b] + column totals -> tot[b].
__global__ __launch_bounds__(256) void colprefix2_kernel(
    int* __restrict__ bh_d, int* __restrict__ bh_s,
    int* __restrict__ tot_d, int* __restrict__ tot_s, int NBLK, int NB) {
    __shared__ int ws[4];
    const int b0 = blockIdx.x * 4;
    const int t = threadIdx.x;
    {
        int carry[4] = {0, 0, 0, 0};
        for (int base = 0; base < NBLK; base += 256) {
            const int r = base + t;
            int v[4];
#pragma unroll
            for (int c = 0; c < 4; ++c)
                v[c] = (r < NBLK && b0 + c < NB)
                           ? bh_d[(size_t)r * NB + b0 + c] : 0;
#pragma unroll
            for (int c = 0; c < 4; ++c) {
                int total;
                const int e = block_excl_scan<4>(v[c], ws, &total);
                if (r < NBLK && b0 + c < NB)
                    bh_d[(size_t)r * NB + b0 + c] = carry[c] + e;
                carry[c] += total;
                __syncthreads();
            }
        }
        if (t == 0)
#pragma unroll
            for (int c = 0; c < 4; ++c)
                if (b0 + c < NB) tot_d[b0 + c] = carry[c];
        __syncthreads();
    }
    {
        int carry[4] = {0, 0, 0, 0};
        for (int base = 0; base < NBLK; base += 256) {
            const int r = base + t;
            int v[4];
#pragma unroll
            for (int c = 0; c < 4; ++c)
                v[c] = (r < NBLK && b0 + c < NB)
                           ? bh_s[(size_t)r * NB + b0 + c] : 0;
#pragma unroll
            for (int c = 0; c < 4; ++c) {
                int total;
                const int e = block_excl_scan<4>(v[c], ws, &total);
                if (r < NBLK && b0 + c < NB)
                    bh_s[(size_t)r * NB + b0 + c] = carry[c] + e;
                carry[c] += total;
                __syncthreads();
            }
        }
        if (t == 0)
#pragma unroll
            for (int c = 0; c < 4; ++c)
                if (b0 + c < NB) tot_s[b0 + c] = carry[c];
    }
}

// K2b: single block: gb_d = excl-scan(tot_d), gb_s = excl-scan(tot_s).
__global__ __launch_bounds__(256) void bscan2_kernel(
    const int* __restrict__ tot_d, const int* __restrict__ tot_s,
    int* __restrict__ gb_d, int* __restrict__ gb_s,
    int* __restrict__ row_ptr, int NB, int N, int E) {
    __shared__ int ws[4];
    const int t = threadIdx.x;
    const int i0 = t * 4;
    {
        int a[4];
#pragma unroll
        for (int u = 0; u < 4; ++u) a[u] = (i0 + u < NB) ? tot_d[i0 + u] : 0;
        int e0 = block_excl_scan<4>(a[0] + a[1] + a[2] + a[3], ws, nullptr);
#pragma unroll
        for (int u = 0; u < 4; ++u) {
            if (i0 + u < NB) gb_d[i0 + u] = e0;
            e0 += a[u];
        }
    }
    __syncthreads();
    {
        int a[4];
#pragma unroll
        for (int u = 0; u < 4; ++u) a[u] = (i0 + u < NB) ? tot_s[i0 + u] : 0;
        int e0 = block_excl_scan<4>(a[0] + a[1] + a[2] + a[3], ws, nullptr);
#pragma unroll
        for (int u = 0; u < 4; ++u) {
            if (i0 + u < NB) gb_s[i0 + u] = e0;
            e0 += a[u];
        }
    }
    if (t == 0) { gb_d[NB] = E; gb_s[NB] = E; row_ptr[N] = E; }
}

// ---------------------------------------------------------------------------
// K3: LDS-staged dual scatter (R7-proven dataflow), 512 threads.
// ---------------------------------------------------------------------------
__global__ __launch_bounds__(512) void scatter2_kernel(
    const int* __restrict__ src, const int* __restrict__ dst,
    const int* __restrict__ bh_d, const int* __restrict__ bh_s,
    const int* __restrict__ gb_d, const int* __restrict__ gb_s,
    unsigned int* __restrict__ ebuf, unsigned char* __restrict__ sbuf,
    int E, int NB) {
    __shared__ unsigned int eb_val[EPB];   // 16 KB payload (u32 / u8 phase B)
    __shared__ int eb_dst[EPB];            // 16 KB global dest indices
    __shared__ int cur[MAXNB];             // count -> local-prefix cursor
    __shared__ int bd[MAXNB];              // (global base) - (local prefix)
    __shared__ int ws[8];
    const int t = threadIdx.x;
    const int base = blockIdx.x * EPB;
    const int end = min(base + EPB, E);
    const int tot = end - base;
    constexpr int ITER = EPB / 512;        // 8 edges per thread

    unsigned sv[ITER];
    int dv[ITER];
    for (int i = t; i < MAXNB; i += 512) cur[i] = 0;
    __syncthreads();
#pragma unroll
    for (int u = 0; u < ITER; ++u) {
        const int e = base + t + u * 512;
        if (e < end) {
            sv[u] = (unsigned)src[e];
            dv[u] = dst[e];
            atomicAdd(&cur[dv[u] >> BK_BITS], 1);
        } else {
            dv[u] = -1;
            sv[u] = 0;
        }
    }
    __syncthreads();

    {
        const int a = cur[t];
        const int e0 = block_excl_scan<8>(a, ws, nullptr);
        const int g = (t < NB)
            ? gb_d[t] + bh_d[(size_t)blockIdx.x * NB + t] : 0;
        cur[t] = e0;
        bd[t] = g - e0;
    }
    __syncthreads();
#pragma unroll
    for (int u = 0; u < ITER; ++u) {
        if (dv[u] >= 0) {
            const int b = dv[u] >> BK_BITS;
            const int pos = atomicAdd(&cur[b], 1);
            eb_val[pos] = (sv[u] << 8) | (unsigned)(dv[u] & (BK_SIZE - 1));
            eb_dst[pos] = bd[b] + pos;
        }
    }
    __syncthreads();
    for (int i = t; i < tot; i += 512)
        ebuf[eb_dst[i]] = eb_val[i];
    __syncthreads();

    for (int i = t; i < MAXNB; i += 512) cur[i] = 0;
    __syncthreads();
#pragma unroll
    for (int u = 0; u < ITER; ++u)
        if (dv[u] >= 0) atomicAdd(&cur[(int)(sv[u] >> BK_BITS)], 1);
    __syncthreads();
    {
        const int a = cur[t];
        const int e0 = block_excl_scan<8>(a, ws, nullptr);
        const int g = (t < NB)
            ? gb_s[t] + bh_s[(size_t)blockIdx.x * NB + t] : 0;
        cur[t] = e0;
        bd[t] = g - e0;
    }
    __syncthreads();
    unsigned char* sb_val = (unsigned char*)eb_val;
#pragma unroll
    for (int u = 0; u < ITER; ++u) {
        if (dv[u] >= 0) {
            const int b = (int)(sv[u] >> BK_BITS);
            const int pos = atomicAdd(&cur[b], 1);
            sb_val[pos] = (unsigned char)(sv[u] & (BK_SIZE - 1));
            eb_dst[pos] = bd[b] + pos;
        }
    }
    __syncthreads();
    for (int i = t; i < tot; i += 512)
        sbuf[eb_dst[i]] = sb_val[i];
}

// K4: per-bucket exact CSR + fused src-side count -> norm_src. 512 threads.
__global__ __launch_bounds__(512) void bucket_csr_kernel(
    const unsigned int* __restrict__ ebuf, const int* __restrict__ gb_d,
    const unsigned char* __restrict__ sbuf, const int* __restrict__ gb_s,
    int* __restrict__ row_ptr, float* __restrict__ norm_dst,
    float* __restrict__ norm_src, int* __restrict__ edge_src, int N) {
    __shared__ int cnt[BK_SIZE];
    __shared__ int lro[BK_SIZE];
    __shared__ int ws[8];
    const int b = blockIdx.x;
    const int t = threadIdx.x;
    const int beg = gb_d[b], end = gb_d[b + 1];
    const int node = b * BK_SIZE + t;

    if (t < BK_SIZE) cnt[t] = 0;
    __syncthreads();
    for (int j = beg + t; j < end; j += 512)
        atomicAdd(&cnt[ebuf[j] & (BK_SIZE - 1)], 1);
    __syncthreads();

    const int v = (t < BK_SIZE) ? cnt[t] : 0;
    const int excl = block_excl_scan<8>(v, ws, nullptr);
    if (t < BK_SIZE) {
        lro[t] = beg + excl;
        if (node < N) {
            row_ptr[node] = beg + excl;
            norm_dst[node] = rsqrtf(fmaxf((float)v, 1.0f));
        }
    }
    __syncthreads();
    if (t < BK_SIZE) cnt[t] = 0;  // reuse as cursor
    __syncthreads();

    for (int j = beg + t; j < end; j += 512) {
        const unsigned int ed = ebuf[j];
        const int dl = ed & (BK_SIZE - 1);
        const int p = atomicAdd(&cnt[dl], 1);
        edge_src[lro[dl] + p] = (int)(ed >> 8);
    }

    __syncthreads();
    if (t < BK_SIZE) cnt[t] = 0;
    __syncthreads();
    const int sb = gb_s[b], se = gb_s[b + 1];
    for (int j = sb + t; j < se; j += 512)
        atomicAdd(&cnt[sbuf[j]], 1);
    __syncthreads();
    if (t < BK_SIZE && node < N)
        norm_src[node] = rsqrtf(fmaxf((float)cnt[t], 1.0f));
}

// ---------------------------------------------------------------------------
// MFMA GEMM: Y[n,OC] = (X[n,128] @ W[128,OC]) * scale[n], Y fp16.
// ---------------------------------------------------------------------------
template <int OC, bool XHALF>
__global__ __launch_bounds__(256) void mfma_gemm_kernel(
    const void* __restrict__ Xv, const _Float16* __restrict__ Wg,
    const float* __restrict__ scale, _Float16* __restrict__ Y, int n) {
    constexpr int K = 128;
    constexpr int NT = OC / 16;
    constexpr int RPB = 128;
    __shared__ _Float16 Wf[NT * 4 * 64 * 8];

    const int tid = threadIdx.x;
    for (int i = tid * 8; i < K * OC; i += 256 * 8)
        *(h8*)&Wf[i] = *(const h8*)&Wg[i];
    __syncthreads();

    const int lane = tid & 63;
    const int wv = tid >> 6;
    const int m = lane & 15, q = lane >> 4;

#pragma unroll
    for (int it = 0; it < RPB / 64; ++it) {
        const int rbase = blockIdx.x * RPB + it * 64 + wv * 16;
        const int lrow = min(rbase + m, n - 1);

        h8 a[4];
        if constexpr (XHALF) {
            const _Float16* X = (const _Float16*)Xv;
            const _Float16* p = &X[(size_t)lrow * K + q * 8];
#pragma unroll
            for (int s = 0; s < 4; ++s) a[s] = *(const h8*)(p + s * 32);
        } else {
            const float* X = (const float*)Xv;
            const float* p = &X[(size_t)lrow * K + q * 8];
#pragma unroll
            for (int s = 0; s < 4; ++s) {
                const float4 u0 = *(const float4*)(p + s * 32);
                const float4 u1 = *(const float4*)(p + s * 32 + 4);
                h8 v;
                v[0] = (_Float16)u0.x; v[1] = (_Float16)u0.y;
                v[2] = (_Float16)u0.z; v[3] = (_Float16)u0.w;
                v[4] = (_Float16)u1.x; v[5] = (_Float16)u1.y;
                v[6] = (_Float16)u1.z; v[7] = (_Float16)u1.w;
                a[s] = v;
            }
        }

        f4v acc[NT];
#pragma unroll
        for (int t = 0; t < NT; ++t) acc[t] = (f4v)0.0f;

#pragma unroll
        for (int s = 0; s < 4; ++s) {
#pragma unroll
            for (int t = 0; t < NT; ++t) {
                const h8 b = *(const h8*)&Wf[((t * 4 + s) * 64 + lane) * 8];
                acc[t] = __builtin_amdgcn_mfma_f32_16x16x32_f16(
                    a[s], b, acc[t], 0, 0, 0);
            }
        }

#pragma unroll
        for (int r = 0; r < 4; ++r) {
            const int orow = rbase + q * 4 + r;
            if (orow < n) {
                const float sc = scale[orow];
#pragma unroll
                for (int t = 0; t < NT; ++t)
                    Y[(size_t)orow * OC + t * 16 + m] =
                        (_Float16)(acc[t][r] * sc);
            }
        }
    }
}

// ---------------------------------------------------------------------------
// shared 16/8/4/1-deep gather-accumulate over fp16 rows.
// ---------------------------------------------------------------------------
template <int TPN>
__device__ inline f8v gather_rows(const h8* __restrict__ T8,
                                  const int* __restrict__ edge_src,
                                  int beg, int end, int f8) {
    f8v acc = (f8v)0.0f;
    int j = beg;
    for (; j + 15 < end; j += 16) {
        int s[16];
#pragma unroll
        for (int u = 0; u < 16; ++u) s[u] = edge_src[j + u];
        h8 a[16];
#pragma unroll
        for (int u = 0; u < 16; ++u) a[u] = T8[(size_t)s[u] * TPN + f8];
#pragma unroll
        for (int u = 0; u < 16; ++u)
            acc += __builtin_convertvector(a[u], f8v);
    }
    for (; j + 7 < end; j += 8) {
        int s[8];
#pragma unroll
        for (int u = 0; u < 8; ++u) s[u] = edge_src[j + u];
        h8 a[8];
#pragma unroll
        for (int u = 0; u < 8; ++u) a[u] = T8[(size_t)s[u] * TPN + f8];
#pragma unroll
        for (int u = 0; u < 8; ++u)
            acc += __builtin_convertvector(a[u], f8v);
    }
    for (; j + 3 < end; j += 4) {
        int s[4];
#pragma unroll
        for (int u = 0; u < 4; ++u) s[u] = edge_src[j + u];
        h8 a[4];
#pragma unroll
        for (int u = 0; u < 4; ++u) a[u] = T8[(size_t)s[u] * TPN + f8];
#pragma unroll
        for (int u = 0; u < 4; ++u)
            acc += __builtin_convertvector(a[u], f8v);
    }
    for (; j < end; ++j)
        acc += __builtin_convertvector(T8[(size_t)edge_src[j] * TPN + f8], f8v);
    return acc;
}

// ---------------------------------------------------------------------------
// pull aggregation + fused epilogue over fp16 rows; [nbeg, nend) node range
// (range-split so each half surfaces separately in rocprof top-k).
// ---------------------------------------------------------------------------
template <int FEAT, bool RELU, bool OUT_HALF>
__global__ __launch_bounds__(256) void gather_agg_kernel(
    const _Float16* __restrict__ T, const int* __restrict__ row_ptr,
    const int* __restrict__ edge_src, const float* __restrict__ norm_dst,
    const float* __restrict__ bias, void* __restrict__ outv,
    int nbeg, int nend) {
    constexpr int TPN = FEAT / 8;
    constexpr int NPB = 256 / TPN;
    const int node = nbeg + blockIdx.x * NPB + threadIdx.x / TPN;
    const int f8 = threadIdx.x % TPN;
    if (node >= nend) return;
    const int beg = row_ptr[node];
    const int end = row_ptr[node + 1];

    f8v acc = gather_rows<TPN>((const h8*)T, edge_src, beg, end, f8);

    const float nd = norm_dst[node];
    float r[8];
#pragma unroll
    for (int k = 0; k < 8; ++k) {
        r[k] = acc[k] * nd + bias[f8 * 8 + k];
        if constexpr (RELU) r[k] = fmaxf(r[k], 0.0f);
    }

    if constexpr (OUT_HALF) {
        _Float16* out = (_Float16*)outv;
        h8 o;
#pragma unroll
        for (int k = 0; k < 8; ++k) o[k] = (_Float16)r[k];
        *(h8*)&out[(size_t)node * FEAT + f8 * 8] = o;
    } else {
        float* out = (float*)outv;
        float4 o0 = make_float4(r[0], r[1], r[2], r[3]);
        float4 o1 = make_float4(r[4], r[5], r[6], r[7]);
        *(float4*)&out[(size_t)node * FEAT + f8 * 8] = o0;
        *(float4*)&out[(size_t)node * FEAT + f8 * 8 + 4] = o1;
    }
}

// ---------------------------------------------------------------------------
// fused layer-1 aggregation + layer-2 GEMM (R3-proven); [nbeg, nend) range.
// ---------------------------------------------------------------------------
template <int FEAT, int OC>
__global__ __launch_bounds__(256) void gather_gemm_kernel(
    const _Float16* __restrict__ T, const int* __restrict__ row_ptr,
    const int* __restrict__ edge_src, const float* __restrict__ norm_dst,
    const float* __restrict__ norm_src, const float* __restrict__ bias,
    const _Float16* __restrict__ Wg, _Float16* __restrict__ Y,
    int nbeg, int nend) {
    constexpr int TPN = FEAT / 8;   // 16 threads per node
    constexpr int NPB = 256 / TPN;  // 16 nodes per block
    constexpr int AP = FEAT + 8;    // padded LDS row, 272 B (2-way alias, free)
    __shared__ _Float16 Ah[NPB * AP];

    const int tid = threadIdx.x;
    const int node = nbeg + blockIdx.x * NPB + tid / TPN;
    const int f8 = tid % TPN;
    const int nl = tid / TPN;

    float r[8];
    if (node < nend) {
        const int beg = row_ptr[node];
        const int end = row_ptr[node + 1];
        f8v acc = gather_rows<TPN>((const h8*)T, edge_src, beg, end, f8);

        const float nd = norm_dst[node];
        const float ns = norm_src[node];
#pragma unroll
        for (int k = 0; k < 8; ++k) {
            float v = acc[k] * nd + bias[f8 * 8 + k];
            v = fmaxf(v, 0.0f);          // relu (layer 1)
            r[k] = v * ns;               // next layer's src scaling
        }
    } else {
#pragma unroll
        for (int k = 0; k < 8; ++k) r[k] = 0.0f;
    }

    {
        h8 av;
#pragma unroll
        for (int k = 0; k < 8; ++k) av[k] = (_Float16)r[k];
        *(h8*)&Ah[nl * AP + f8 * 8] = av;
    }
    __syncthreads();

    // ---- 16x64 GEMM: wave w -> output cols [w*16, w*16+16) ----
    const int lane = tid & 63, w = tid >> 6;
    const int m = lane & 15, q = lane >> 4;
    f4v acc2 = (f4v)0.0f;
#pragma unroll
    for (int s = 0; s < 4; ++s) {
        const h8 a = *(const h8*)&Ah[m * AP + s * 32 + q * 8];
        const h8 b = *(const h8*)&Wg[((w * 4 + s) * 64 + lane) * 8];
        acc2 = __builtin_amdgcn_mfma_f32_16x16x32_f16(a, b, acc2, 0, 0, 0);
    }
#pragma unroll
    for (int rr = 0; rr < 4; ++rr) {
        const int orow = nbeg + blockIdx.x * NPB + q * 4 + rr;
        if (orow < nend)
            Y[(size_t)orow * OC + w * 16 + m] = (_Float16)acc2[rr];
    }
}

extern "C" void kernel_launch(void* const* d_in, const int* in_sizes, int n_in,
                              void* d_out, int out_size, void* d_ws, size_t ws_size,
                              hipStream_t stream) {
    const float* x   = (const float*)d_in[0];   // [N,128]
    const int*   src = (const int*)d_in[1];     // [E]
    const int*   dst = (const int*)d_in[2];     // [E]
    const float* W1  = (const float*)d_in[3];   // [128,128]
    const float* b1  = (const float*)d_in[4];   // [128]
    const float* W2  = (const float*)d_in[5];   // [128,64]
    const float* b2  = (const float*)d_in[6];   // [64]
    float* out = (float*)d_out;

    const int N = in_sizes[0] / N_FEATS_IN;     // 100000
    const int E = in_sizes[1];                  // 1600000
    const int NB = (N + BK_SIZE - 1) / BK_SIZE; // 391 buckets
    const int NBLK = (E + EPB - 1) / EPB;       // 391 edge blocks

    auto align4 = [](size_t w) { return (w + 3) & ~(size_t)3; };
    char* base = (char*)d_ws;
    size_t off = 0;
    auto take = [&](size_t words) {
        char* p = base + off * 4;
        off = align4(off + words);
        return p;
    };
    int*   tot_d    = (int*)take(NB);
    int*   tot_s    = (int*)take(NB);
    int*   gb_d     = (int*)take(NB + 1);
    int*   gb_s     = (int*)take(NB + 1);
    int*   bh_d     = (int*)take((size_t)NBLK * NB);
    int*   bh_s     = (int*)take((size_t)NBLK * NB);
    unsigned int*  ebuf = (unsigned int*)take(E);
    unsigned char* sbuf = (unsigned char*)take((E + 3) / 4);
    int*   row_ptr  = (int*)take(N + 1);
    int*   edge_src = (int*)take(E);
    float* norms    = (float*)take(2 * (size_t)N);
    _Float16* t1    = (_Float16*)take((size_t)N * 64);  // N x 128 fp16
    _Float16* t2    = (_Float16*)take((size_t)N * 32);  // N x 64  fp16
    _Float16* wf1g  = (_Float16*)take(128 * 128 / 2);   // pre-swizzled W1 fp16
    _Float16* wf2g  = (_Float16*)take(128 * 64 / 2);    // pre-swizzled W2 fp16
    float* norm_src = norms;
    float* norm_dst = norms + N;

    // ---- CSR build (dual counting sort; zero global atomics; 5 kernels) ----
    hist_kernel<<<NBLK, 512, 0, stream>>>(src, dst, bh_d, bh_s,
                                          W1, W2, wf1g, wf2g, E, NB);
    colprefix2_kernel<<<(NB + 3) / 4, 256, 0, stream>>>(bh_d, bh_s,
                                                        tot_d, tot_s,
                                                        NBLK, NB);
    bscan2_kernel<<<1, 256, 0, stream>>>(tot_d, tot_s, gb_d, gb_s, row_ptr,
                                         NB, N, E);
    scatter2_kernel<<<NBLK, 512, 0, stream>>>(src, dst, bh_d, bh_s, gb_d, gb_s,
                                              ebuf, sbuf, E, NB);
    bucket_csr_kernel<<<NB, 512, 0, stream>>>(ebuf, gb_d, sbuf, gb_s, row_ptr,
                                              norm_dst, norm_src, edge_src, N);

    // ---- layer 1 GEMM: t1 = (x @ W1) * norm_src ----
    mfma_gemm_kernel<128, false><<<(N + 127) / 128, 256, 0, stream>>>(
        x, wf1g, norm_src, t1, N);

    // ---- fused: aggregate(t1) -> +b1, relu, *norm_src -> @W2 -> t2 ----
    // (split in two node-range halves so each surfaces in rocprof top-k)
    const int NH = ((N / 2) + 15) & ~15;        // 16-aligned midpoint
    gather_gemm_kernel<128, 64><<<(NH + 15) / 16, 256, 0, stream>>>(
        t1, row_ptr, edge_src, norm_dst, norm_src, b1, wf2g, t2, 0, NH);
    gather_gemm_kernel<128, 64><<<(N - NH + 15) / 16, 256, 0, stream>>>(
        t1, row_ptr, edge_src, norm_dst, norm_src, b1, wf2g, t2, NH, N);

    // ---- layer 2 aggregation -> final output (same split) ----
    const int NH2 = ((N / 2) + 31) & ~31;       // 32-aligned midpoint
    gather_agg_kernel<64, false, false><<<(NH2 + 31) / 32, 256, 0, stream>>>(
        t2, row_ptr, edge_src, norm_dst, b2, out, 0, NH2);
    gather_agg_kernel<64, false, false><<<(N - NH2 + 31) / 32, 256, 0, stream>>>(
        t2, row_ptr, edge_src, norm_dst, b2, out, NH2, N);
}

// Round 12
// 288.195 us; speedup vs baseline: 1.0426x; 1.0426x over previous
//
#include <hip/hip_runtime.h>
#include <hip/hip_bf16.h>

#define N_FEATS_IN 128
#define BK_BITS 8
#define BK_SIZE 256      // nodes per bucket
#define EPB 4096         // edges per histogram/scatter block
#define MAXNB 512        // max buckets (N <= 131072)

typedef _Float16 h8 __attribute__((ext_vector_type(8)));
typedef float    f4v __attribute__((ext_vector_type(4)));
typedef float    f8v __attribute__((ext_vector_type(8)));

// ---------------------------------------------------------------------------
// scan / reduce helpers
// ---------------------------------------------------------------------------
__device__ inline int wave_incl_scan(int v) {
    const int lane = threadIdx.x & 63;
    for (int off = 1; off < 64; off <<= 1) {
        int u = __shfl_up(v, off, 64);
        if (lane >= off) v += u;
    }
    return v;
}

// NW-wave (NW*64-thread) block exclusive scan; ws = LDS int[NW]; syncs
// internally after the ws write. Caller must __syncthreads() before reuse.
template <int NW>
__device__ inline int block_excl_scan(int s, int* ws, int* total) {
    const int lane = threadIdx.x & 63, wid = threadIdx.x >> 6;
    int inc = wave_incl_scan(s);
    if (lane == 63) ws[wid] = inc;
    __syncthreads();
    int woff = 0;
#pragma unroll
    for (int w = 0; w < NW; ++w) woff += (w < wid) ? ws[w] : 0;
    if (total) {
        int tt = 0;
#pragma unroll
        for (int w = 0; w < NW; ++w) tt += ws[w];
        *total = tt;
    }
    return woff + inc - s;
}

// ---------------------------------------------------------------------------
// K1: per-block LDS bucket histograms of dst>>8 AND src>>8 (no global
//     atomics). 512 threads. + fused one-shot W1/W2 pre-swizzle.
// ---------------------------------------------------------------------------
__global__ __launch_bounds__(512) void hist_kernel(
    const int* __restrict__ src, const int* __restrict__ dst,
    int* __restrict__ bh_d, int* __restrict__ bh_s,
    const float* __restrict__ W1, const float* __restrict__ W2,
    _Float16* __restrict__ wf1g, _Float16* __restrict__ wf2g,
    int E, int NB) {
    __shared__ int hd[MAXNB];
    __shared__ int hs[MAXNB];
    const int t = threadIdx.x;

    // ---- W pre-swizzle: B-fragment layout of mfma_f32_16x16x32_f16 ----
    const int widx = blockIdx.x * 512 + t;
    if (widx < 128 * 128) {                       // W1: K=128, OC=128
        const int i = widx;
        const int k = i >> 7, c = i & 127;
        const int tt = c >> 4, s = k >> 5, q = (k >> 3) & 3, j = k & 7;
        wf1g[(((tt * 4 + s) * 4 + q) * 16 + (c & 15)) * 8 + j] =
            (_Float16)W1[i];
    } else if (widx < 128 * 128 + 128 * 64) {     // W2: K=128, OC=64
        const int i = widx - 128 * 128;
        const int k = i >> 6, c = i & 63;
        const int tt = c >> 4, s = k >> 5, q = (k >> 3) & 3, j = k & 7;
        wf2g[(((tt * 4 + s) * 4 + q) * 16 + (c & 15)) * 8 + j] =
            (_Float16)W2[i];
    }

    for (int i = t; i < NB; i += 512) { hd[i] = 0; hs[i] = 0; }
    __syncthreads();
    const int base = blockIdx.x * EPB;
    const int end = min(base + EPB, E);
    for (int e = base + t; e < end; e += 512) {
        atomicAdd(&hd[dst[e] >> BK_BITS], 1);
        atomicAdd(&hs[src[e] >> BK_BITS], 1);
    }
    __syncthreads();
    for (int i = t; i < NB; i += 512) {
        bh_d[(size_t)blockIdx.x * NB + i] = hd[i];
        bh_s[(size_t)blockIdx.x * NB + i] = hs[i];
    }
}

// K2: 4 columns per block (adjacent cols share 64B lines): in-place local
//     exclusive prefix over blk of bh[blk][b] + column totals -> tot[b].
__global__ __launch_bounds__(256) void colprefix2_kernel(
    int* __restrict__ bh_d, int* __restrict__ bh_s,
    int* __restrict__ tot_d, int* __restrict__ tot_s, int NBLK, int NB) {
    __shared__ int ws[4];
    const int b0 = blockIdx.x * 4;
    const int t = threadIdx.x;
    {
        int carry[4] = {0, 0, 0, 0};
        for (int base = 0; base < NBLK; base += 256) {
            const int r = base + t;
            int v[4];
#pragma unroll
            for (int c = 0; c < 4; ++c)
                v[c] = (r < NBLK && b0 + c < NB)
                           ? bh_d[(size_t)r * NB + b0 + c] : 0;
#pragma unroll
            for (int c = 0; c < 4; ++c) {
                int total;
                const int e = block_excl_scan<4>(v[c], ws, &total);
                if (r < NBLK && b0 + c < NB)
                    bh_d[(size_t)r * NB + b0 + c] = carry[c] + e;
                carry[c] += total;
                __syncthreads();
            }
        }
        if (t == 0)
#pragma unroll
            for (int c = 0; c < 4; ++c)
                if (b0 + c < NB) tot_d[b0 + c] = carry[c];
        __syncthreads();
    }
    {
        int carry[4] = {0, 0, 0, 0};
        for (int base = 0; base < NBLK; base += 256) {
            const int r = base + t;
            int v[4];
#pragma unroll
            for (int c = 0; c < 4; ++c)
                v[c] = (r < NBLK && b0 + c < NB)
                           ? bh_s[(size_t)r * NB + b0 + c] : 0;
#pragma unroll
            for (int c = 0; c < 4; ++c) {
                int total;
                const int e = block_excl_scan<4>(v[c], ws, &total);
                if (r < NBLK && b0 + c < NB)
                    bh_s[(size_t)r * NB + b0 + c] = carry[c] + e;
                carry[c] += total;
                __syncthreads();
            }
        }
        if (t == 0)
#pragma unroll
            for (int c = 0; c < 4; ++c)
                if (b0 + c < NB) tot_s[b0 + c] = carry[c];
    }
}

// ---------------------------------------------------------------------------
// K3: LDS-staged dual scatter, 512 threads. Bucket bases gb[] are
// RECOMPUTED PER BLOCK from tot_d/tot_s via one 512-wide register scan
// (replaces the separate bscan dispatch; thread t holds gb[t]).
// ---------------------------------------------------------------------------
__global__ __launch_bounds__(512) void scatter2_kernel(
    const int* __restrict__ src, const int* __restrict__ dst,
    const int* __restrict__ bh_d, const int* __restrict__ bh_s,
    const int* __restrict__ tot_d, const int* __restrict__ tot_s,
    unsigned int* __restrict__ ebuf, unsigned char* __restrict__ sbuf,
    int E, int NB) {
    __shared__ unsigned int eb_val[EPB];   // 16 KB payload (u32 / u8 phase B)
    __shared__ int eb_dst[EPB];            // 16 KB global dest indices
    __shared__ int cur[MAXNB];             // count -> local-prefix cursor
    __shared__ int bd[MAXNB];              // (global base) - (local prefix)
    __shared__ int ws[8];
    const int t = threadIdx.x;
    const int base = blockIdx.x * EPB;
    const int end = min(base + EPB, E);
    const int tot = end - base;
    constexpr int ITER = EPB / 512;        // 8 edges per thread

    // ---- per-block bucket-base scan (thread t holds gb_d[t], gb_s[t]) ----
    const int totd = (t < NB) ? tot_d[t] : 0;
    const int tots = (t < NB) ? tot_s[t] : 0;
    const int gbd = block_excl_scan<8>(totd, ws, nullptr);
    __syncthreads();
    const int gbs = block_excl_scan<8>(tots, ws, nullptr);
    __syncthreads();

    unsigned sv[ITER];
    int dv[ITER];
    for (int i = t; i < MAXNB; i += 512) cur[i] = 0;
    __syncthreads();
#pragma unroll
    for (int u = 0; u < ITER; ++u) {
        const int e = base + t + u * 512;
        if (e < end) {
            sv[u] = (unsigned)src[e];
            dv[u] = dst[e];
            atomicAdd(&cur[dv[u] >> BK_BITS], 1);
        } else {
            dv[u] = -1;
            sv[u] = 0;
        }
    }
    __syncthreads();

    {
        const int a = cur[t];
        const int e0 = block_excl_scan<8>(a, ws, nullptr);
        const int g = (t < NB)
            ? gbd + bh_d[(size_t)blockIdx.x * NB + t] : 0;
        cur[t] = e0;
        bd[t] = g - e0;
    }
    __syncthreads();
#pragma unroll
    for (int u = 0; u < ITER; ++u) {
        if (dv[u] >= 0) {
            const int b = dv[u] >> BK_BITS;
            const int pos = atomicAdd(&cur[b], 1);
            eb_val[pos] = (sv[u] << 8) | (unsigned)(dv[u] & (BK_SIZE - 1));
            eb_dst[pos] = bd[b] + pos;
        }
    }
    __syncthreads();
    for (int i = t; i < tot; i += 512)
        ebuf[eb_dst[i]] = eb_val[i];
    __syncthreads();

    // ---- src side: same flow, 1B payload (reuse LDS) ----
    for (int i = t; i < MAXNB; i += 512) cur[i] = 0;
    __syncthreads();
#pragma unroll
    for (int u = 0; u < ITER; ++u)
        if (dv[u] >= 0) atomicAdd(&cur[(int)(sv[u] >> BK_BITS)], 1);
    __syncthreads();
    {
        const int a = cur[t];
        const int e0 = block_excl_scan<8>(a, ws, nullptr);
        const int g = (t < NB)
            ? gbs + bh_s[(size_t)blockIdx.x * NB + t] : 0;
        cur[t] = e0;
        bd[t] = g - e0;
    }
    __syncthreads();
    unsigned char* sb_val = (unsigned char*)eb_val;
#pragma unroll
    for (int u = 0; u < ITER; ++u) {
        if (dv[u] >= 0) {
            const int b = (int)(sv[u] >> BK_BITS);
            const int pos = atomicAdd(&cur[b], 1);
            sb_val[pos] = (unsigned char)(sv[u] & (BK_SIZE - 1));
            eb_dst[pos] = bd[b] + pos;
        }
    }
    __syncthreads();
    for (int i = t; i < tot; i += 512)
        sbuf[eb_dst[i]] = sb_val[i];
}

// K4: per-bucket exact CSR + fused src-side count -> norm_src. 512 threads.
//     Bucket ranges recomputed per block from tot_d/tot_s (no gb arrays).
__global__ __launch_bounds__(512) void bucket_csr_kernel(
    const unsigned int* __restrict__ ebuf,
    const unsigned char* __restrict__ sbuf,
    const int* __restrict__ tot_d, const int* __restrict__ tot_s,
    int* __restrict__ row_ptr, float* __restrict__ norm_dst,
    float* __restrict__ norm_src, int* __restrict__ edge_src,
    int N, int E, int NB) {
    __shared__ int cnt[BK_SIZE];
    __shared__ int lro[BK_SIZE];
    __shared__ int ws[8];
    __shared__ int sbx[4];   // beg_d, end_d, beg_s, end_s
    const int b = blockIdx.x;
    const int t = threadIdx.x;
    const int node = b * BK_SIZE + t;

    if (b == 0 && t == 0) row_ptr[N] = E;

    // ---- per-block bucket-base scan; thread b broadcasts its range ----
    {
        const int a = (t < NB) ? tot_d[t] : 0;
        const int e0 = block_excl_scan<8>(a, ws, nullptr);
        if (t == b) { sbx[0] = e0; sbx[1] = e0 + a; }
        __syncthreads();
        const int a2 = (t < NB) ? tot_s[t] : 0;
        const int e2 = block_excl_scan<8>(a2, ws, nullptr);
        if (t == b) { sbx[2] = e2; sbx[3] = e2 + a2; }
        __syncthreads();
    }
    const int beg = sbx[0], end = sbx[1];

    if (t < BK_SIZE) cnt[t] = 0;
    __syncthreads();
    for (int j = beg + t; j < end; j += 512)
        atomicAdd(&cnt[ebuf[j] & (BK_SIZE - 1)], 1);
    __syncthreads();

    const int v = (t < BK_SIZE) ? cnt[t] : 0;
    const int excl = block_excl_scan<8>(v, ws, nullptr);
    if (t < BK_SIZE) {
        lro[t] = beg + excl;
        if (node < N) {
            row_ptr[node] = beg + excl;
            norm_dst[node] = rsqrtf(fmaxf((float)v, 1.0f));
        }
    }
    __syncthreads();
    if (t < BK_SIZE) cnt[t] = 0;  // reuse as cursor
    __syncthreads();

    for (int j = beg + t; j < end; j += 512) {
        const unsigned int ed = ebuf[j];
        const int dl = ed & (BK_SIZE - 1);
        const int p = atomicAdd(&cnt[dl], 1);
        edge_src[lro[dl] + p] = (int)(ed >> 8);
    }

    __syncthreads();
    if (t < BK_SIZE) cnt[t] = 0;
    __syncthreads();
    const int sb = sbx[2], se = sbx[3];
    for (int j = sb + t; j < se; j += 512)
        atomicAdd(&cnt[sbuf[j]], 1);
    __syncthreads();
    if (t < BK_SIZE && node < N)
        norm_src[node] = rsqrtf(fmaxf((float)cnt[t], 1.0f));
}

// ---------------------------------------------------------------------------
// MFMA GEMM: Y[n,OC] = (X[n,128] @ W[128,OC]) * scale[n], Y fp16.
// ---------------------------------------------------------------------------
template <int OC, bool XHALF>
__global__ __launch_bounds__(256) void mfma_gemm_kernel(
    const void* __restrict__ Xv, const _Float16* __restrict__ Wg,
    const float* __restrict__ scale, _Float16* __restrict__ Y, int n) {
    constexpr int K = 128;
    constexpr int NT = OC / 16;
    constexpr int RPB = 128;
    __shared__ _Float16 Wf[NT * 4 * 64 * 8];

    const int tid = threadIdx.x;
    for (int i = tid * 8; i < K * OC; i += 256 * 8)
        *(h8*)&Wf[i] = *(const h8*)&Wg[i];
    __syncthreads();

    const int lane = tid & 63;
    const int wv = tid >> 6;
    const int m = lane & 15, q = lane >> 4;

#pragma unroll
    for (int it = 0; it < RPB / 64; ++it) {
        const int rbase = blockIdx.x * RPB + it * 64 + wv * 16;
        const int lrow = min(rbase + m, n - 1);

        h8 a[4];
        if constexpr (XHALF) {
            const _Float16* X = (const _Float16*)Xv;
            const _Float16* p = &X[(size_t)lrow * K + q * 8];
#pragma unroll
            for (int s = 0; s < 4; ++s) a[s] = *(const h8*)(p + s * 32);
        } else {
            const float* X = (const float*)Xv;
            const float* p = &X[(size_t)lrow * K + q * 8];
#pragma unroll
            for (int s = 0; s < 4; ++s) {
                const float4 u0 = *(const float4*)(p + s * 32);
                const float4 u1 = *(const float4*)(p + s * 32 + 4);
                h8 v;
                v[0] = (_Float16)u0.x; v[1] = (_Float16)u0.y;
                v[2] = (_Float16)u0.z; v[3] = (_Float16)u0.w;
                v[4] = (_Float16)u1.x; v[5] = (_Float16)u1.y;
                v[6] = (_Float16)u1.z; v[7] = (_Float16)u1.w;
                a[s] = v;
            }
        }

        f4v acc[NT];
#pragma unroll
        for (int t = 0; t < NT; ++t) acc[t] = (f4v)0.0f;

#pragma unroll
        for (int s = 0; s < 4; ++s) {
#pragma unroll
            for (int t = 0; t < NT; ++t) {
                const h8 b = *(const h8*)&Wf[((t * 4 + s) * 64 + lane) * 8];
                acc[t] = __builtin_amdgcn_mfma_f32_16x16x32_f16(
                    a[s], b, acc[t], 0, 0, 0);
            }
        }

#pragma unroll
        for (int r = 0; r < 4; ++r) {
            const int orow = rbase + q * 4 + r;
            if (orow < n) {
                const float sc = scale[orow];
#pragma unroll
                for (int t = 0; t < NT; ++t)
                    Y[(size_t)orow * OC + t * 16 + m] =
                        (_Float16)(acc[t][r] * sc);
            }
        }
    }
}

// ---------------------------------------------------------------------------
// shared 16/8/4/1-deep gather-accumulate over fp16 rows.
// ---------------------------------------------------------------------------
template <int TPN>
__device__ inline f8v gather_rows(const h8* __restrict__ T8,
                                  const int* __restrict__ edge_src,
                                  int beg, int end, int f8) {
    f8v acc = (f8v)0.0f;
    int j = beg;
    for (; j + 15 < end; j += 16) {
        int s[16];
#pragma unroll
        for (int u = 0; u < 16; ++u) s[u] = edge_src[j + u];
        h8 a[16];
#pragma unroll
        for (int u = 0; u < 16; ++u) a[u] = T8[(size_t)s[u] * TPN + f8];
#pragma unroll
        for (int u = 0; u < 16; ++u)
            acc += __builtin_convertvector(a[u], f8v);
    }
    for (; j + 7 < end; j += 8) {
        int s[8];
#pragma unroll
        for (int u = 0; u < 8; ++u) s[u] = edge_src[j + u];
        h8 a[8];
#pragma unroll
        for (int u = 0; u < 8; ++u) a[u] = T8[(size_t)s[u] * TPN + f8];
#pragma unroll
        for (int u = 0; u < 8; ++u)
            acc += __builtin_convertvector(a[u], f8v);
    }
    for (; j + 3 < end; j += 4) {
        int s[4];
#pragma unroll
        for (int u = 0; u < 4; ++u) s[u] = edge_src[j + u];
        h8 a[4];
#pragma unroll
        for (int u = 0; u < 4; ++u) a[u] = T8[(size_t)s[u] * TPN + f8];
#pragma unroll
        for (int u = 0; u < 4; ++u)
            acc += __builtin_convertvector(a[u], f8v);
    }
    for (; j < end; ++j)
        acc += __builtin_convertvector(T8[(size_t)edge_src[j] * TPN + f8], f8v);
    return acc;
}

// ---------------------------------------------------------------------------
// pull aggregation + fused epilogue over fp16 rows
// ---------------------------------------------------------------------------
template <int FEAT, bool RELU, bool OUT_HALF>
__global__ __launch_bounds__(256) void gather_agg_kernel(
    const _Float16* __restrict__ T, const int* __restrict__ row_ptr,
    const int* __restrict__ edge_src, const float* __restrict__ norm_dst,
    const float* __restrict__ bias, void* __restrict__ outv, int n) {
    constexpr int TPN = FEAT / 8;
    constexpr int NPB = 256 / TPN;
    const int node = blockIdx.x * NPB + threadIdx.x / TPN;
    const int f8 = threadIdx.x % TPN;
    if (node >= n) return;
    const int beg = row_ptr[node];
    const int end = row_ptr[node + 1];

    f8v acc = gather_rows<TPN>((const h8*)T, edge_src, beg, end, f8);

    const float nd = norm_dst[node];
    float r[8];
#pragma unroll
    for (int k = 0; k < 8; ++k) {
        r[k] = acc[k] * nd + bias[f8 * 8 + k];
        if constexpr (RELU) r[k] = fmaxf(r[k], 0.0f);
    }

    if constexpr (OUT_HALF) {
        _Float16* out = (_Float16*)outv;
        h8 o;
#pragma unroll
        for (int k = 0; k < 8; ++k) o[k] = (_Float16)r[k];
        *(h8*)&out[(size_t)node * FEAT + f8 * 8] = o;
    } else {
        float* out = (float*)outv;
        float4 o0 = make_float4(r[0], r[1], r[2], r[3]);
        float4 o1 = make_float4(r[4], r[5], r[6], r[7]);
        *(float4*)&out[(size_t)node * FEAT + f8 * 8] = o0;
        *(float4*)&out[(size_t)node * FEAT + f8 * 8 + 4] = o1;
    }
}

// ---------------------------------------------------------------------------
// fused layer-1 aggregation + layer-2 GEMM (R3-proven).
// ---------------------------------------------------------------------------
template <int FEAT, int OC>
__global__ __launch_bounds__(256) void gather_gemm_kernel(
    const _Float16* __restrict__ T, const int* __restrict__ row_ptr,
    const int* __restrict__ edge_src, const float* __restrict__ norm_dst,
    const float* __restrict__ norm_src, const float* __restrict__ bias,
    const _Float16* __restrict__ Wg, _Float16* __restrict__ Y, int n) {
    constexpr int TPN = FEAT / 8;   // 16 threads per node
    constexpr int NPB = 256 / TPN;  // 16 nodes per block
    constexpr int AP = FEAT + 8;    // padded LDS row, 272 B (2-way alias, free)
    __shared__ _Float16 Ah[NPB * AP];

    const int tid = threadIdx.x;
    const int node = blockIdx.x * NPB + tid / TPN;
    const int f8 = tid % TPN;
    const int nl = tid / TPN;

    float r[8];
    if (node < n) {
        const int beg = row_ptr[node];
        const int end = row_ptr[node + 1];
        f8v acc = gather_rows<TPN>((const h8*)T, edge_src, beg, end, f8);

        const float nd = norm_dst[node];
        const float ns = norm_src[node];
#pragma unroll
        for (int k = 0; k < 8; ++k) {
            float v = acc[k] * nd + bias[f8 * 8 + k];
            v = fmaxf(v, 0.0f);          // relu (layer 1)
            r[k] = v * ns;               // next layer's src scaling
        }
    } else {
#pragma unroll
        for (int k = 0; k < 8; ++k) r[k] = 0.0f;
    }

    {
        h8 av;
#pragma unroll
        for (int k = 0; k < 8; ++k) av[k] = (_Float16)r[k];
        *(h8*)&Ah[nl * AP + f8 * 8] = av;
    }
    __syncthreads();

    // ---- 16x64 GEMM: wave w -> output cols [w*16, w*16+16) ----
    const int lane = tid & 63, w = tid >> 6;
    const int m = lane & 15, q = lane >> 4;
    f4v acc2 = (f4v)0.0f;
#pragma unroll
    for (int s = 0; s < 4; ++s) {
        const h8 a = *(const h8*)&Ah[m * AP + s * 32 + q * 8];
        const h8 b = *(const h8*)&Wg[((w * 4 + s) * 64 + lane) * 8];
        acc2 = __builtin_amdgcn_mfma_f32_16x16x32_f16(a, b, acc2, 0, 0, 0);
    }
#pragma unroll
    for (int rr = 0; rr < 4; ++rr) {
        const int orow = blockIdx.x * NPB + q * 4 + rr;
        if (orow < n)
            Y[(size_t)orow * OC + w * 16 + m] = (_Float16)acc2[rr];
    }
}

extern "C" void kernel_launch(void* const* d_in, const int* in_sizes, int n_in,
                              void* d_out, int out_size, void* d_ws, size_t ws_size,
                              hipStream_t stream) {
    const float* x   = (const float*)d_in[0];   // [N,128]
    const int*   src = (const int*)d_in[1];     // [E]
    const int*   dst = (const int*)d_in[2];     // [E]
    const float* W1  = (const float*)d_in[3];   // [128,128]
    const float* b1  = (const float*)d_in[4];   // [128]
    const float* W2  = (const float*)d_in[5];   // [128,64]
    const float* b2  = (const float*)d_in[6];   // [64]
    float* out = (float*)d_out;

    const int N = in_sizes[0] / N_FEATS_IN;     // 100000
    const int E = in_sizes[1];                  // 1600000
    const int NB = (N + BK_SIZE - 1) / BK_SIZE; // 391 buckets
    const int NBLK = (E + EPB - 1) / EPB;       // 391 edge blocks

    auto align4 = [](size_t w) { return (w + 3) & ~(size_t)3; };
    char* base = (char*)d_ws;
    size_t off = 0;
    auto take = [&](size_t words) {
        char* p = base + off * 4;
        off = align4(off + words);
        return p;
    };
    int*   tot_d    = (int*)take(NB);
    int*   tot_s    = (int*)take(NB);
    int*   bh_d     = (int*)take((size_t)NBLK * NB);
    int*   bh_s     = (int*)take((size_t)NBLK * NB);
    unsigned int*  ebuf = (unsigned int*)take(E);
    unsigned char* sbuf = (unsigned char*)take((E + 3) / 4);
    int*   row_ptr  = (int*)take(N + 1);
    int*   edge_src = (int*)take(E);
    float* norms    = (float*)take(2 * (size_t)N);
    _Float16* t1    = (_Float16*)take((size_t)N * 64);  // N x 128 fp16
    _Float16* t2    = (_Float16*)take((size_t)N * 32);  // N x 64  fp16
    _Float16* wf1g  = (_Float16*)take(128 * 128 / 2);   // pre-swizzled W1 fp16
    _Float16* wf2g  = (_Float16*)take(128 * 64 / 2);    // pre-swizzled W2 fp16
    float* norm_src = norms;
    float* norm_dst = norms + N;

    // ---- CSR build (dual counting sort; 4 kernels, no bscan dispatch) ----
    hist_kernel<<<NBLK, 512, 0, stream>>>(src, dst, bh_d, bh_s,
                                          W1, W2, wf1g, wf2g, E, NB);
    colprefix2_kernel<<<(NB + 3) / 4, 256, 0, stream>>>(bh_d, bh_s,
                                                        tot_d, tot_s,
                                                        NBLK, NB);
    scatter2_kernel<<<NBLK, 512, 0, stream>>>(src, dst, bh_d, bh_s,
                                              tot_d, tot_s, ebuf, sbuf, E, NB);
    bucket_csr_kernel<<<NB, 512, 0, stream>>>(ebuf, sbuf, tot_d, tot_s,
                                              row_ptr, norm_dst, norm_src,
                                              edge_src, N, E, NB);

    // ---- layer 1 GEMM: t1 = (x @ W1) * norm_src ----
    mfma_gemm_kernel<128, false><<<(N + 127) / 128, 256, 0, stream>>>(
        x, wf1g, norm_src, t1, N);

    // ---- fused: aggregate(t1) -> +b1, relu, *norm_src -> @W2 -> t2 ----
    gather_gemm_kernel<128, 64><<<(N + 15) / 16, 256, 0, stream>>>(
        t1, row_ptr, edge_src, norm_dst, norm_src, b1, wf2g, t2, N);

    // ---- layer 2 aggregation -> final output ----
    gather_agg_kernel<64, false, false><<<(N + 31) / 32, 256, 0, stream>>>(
        t2, row_ptr, edge_src, norm_dst, b2, out, N);
}